// Round 9
// baseline (225.298 us; speedup 1.0000x reference)
//
#include <hip/hip_runtime.h>
#include <hip/hip_bf16.h>
#include <stdint.h>

// LoRA int8-dequant linear, MI355X/gfx950 — int8 main path, 32x32x32 MFMA.
//   Xi8[8192][4096] = rne(x * 127/absmax_row),  tstep[m] = absmax_row/127
//   Wi8[4096][4096] = qweight codes (exact i8)
//   out = (Xi8 @ Wi8^T)_i32 * (tstep[m]*scale[o]) + xa @ (2B)^T
// Main GEMM: 256x256 tile, BK=64, 8 waves x (128x64), mfma_i32_32x32x32_i8
// (16 MFMA/wave/tile — half the issue count of 16x16x64), 3-deep LDS (96 KB),
// counted vmcnt(4), 1 barrier/K-tile. LoRA epilogue via mfma_f32_32x32x16_bf16
// (same C/D layout, dtype-independent).

typedef __bf16 bf16x8 __attribute__((ext_vector_type(8)));
typedef float f32x4 __attribute__((ext_vector_type(4)));
typedef float f32x16 __attribute__((ext_vector_type(16)));
typedef int i32x4 __attribute__((ext_vector_type(4)));
typedef int i32x16 __attribute__((ext_vector_type(16)));

#define DIN   4096
#define DOUT  4096
#define MTOT  8192
#define RNK   64
#define NT    64
#define BUFB  32768   // 32 KB per LDS buffer (A 16K + B 16K)

__device__ inline void gload_lds16(const void* g, void* l) {
  __builtin_amdgcn_global_load_lds((const __attribute__((address_space(1))) void*)g,
                                   (__attribute__((address_space(3))) void*)l,
                                   16, 0, 0);
}

// ==== merged prep: blocks [0,8192) quant x rows; [8192,8256) quant lora_A
// rows; [8256,8512) Blt = bf16(2*lora_B); [8512,24896) Wi8 = i8(qweight) ====
__global__ __launch_bounds__(256) void prep_kernel(const float* __restrict__ x,
                                                   const int* __restrict__ qw,
                                                   const float* __restrict__ lA,
                                                   const float* __restrict__ lB,
                                                   signed char* __restrict__ Xi8,
                                                   float* __restrict__ tstep,
                                                   signed char* __restrict__ Wi8,
                                                   signed char* __restrict__ Ai8,
                                                   float* __restrict__ astep,
                                                   __bf16* __restrict__ Blt) {
  const int bid = blockIdx.x, t = threadIdx.x;
  const float* src = nullptr;
  signed char* dst = nullptr;
  float* stp = nullptr;
  int row = 0;
  if (bid < 8192) { src = x; dst = Xi8; stp = tstep; row = bid; }
  else if (bid < 8256) { src = lA; dst = Ai8; stp = astep; row = bid - 8192; }
  if (src) {
    const float4* xr = (const float4*)(src + (size_t)row * DIN);
    float4 v[4];
    float m = 0.f;
#pragma unroll
    for (int s = 0; s < 4; ++s) {
      v[s] = xr[t + s * 256];
      m = fmaxf(m, fmaxf(fmaxf(fabsf(v[s].x), fabsf(v[s].y)),
                         fmaxf(fabsf(v[s].z), fabsf(v[s].w))));
    }
#pragma unroll
    for (int off = 32; off > 0; off >>= 1) m = fmaxf(m, __shfl_xor(m, off));
    __shared__ float wm[4];
    if ((t & 63) == 0) wm[t >> 6] = m;
    __syncthreads();
    m = fmaxf(fmaxf(wm[0], wm[1]), fmaxf(wm[2], wm[3]));
    m = fmaxf(m, 1e-30f);
    const float rs = 127.0f / m;
    int* orow = (int*)(dst + (size_t)row * DIN);
#pragma unroll
    for (int s = 0; s < 4; ++s) {
      float e[4] = {v[s].x, v[s].y, v[s].z, v[s].w};
      union { signed char c[4]; int i; } p;
#pragma unroll
      for (int j = 0; j < 4; ++j) {
        int q = __float2int_rn(e[j] * rs);
        q = q > 127 ? 127 : (q < -127 ? -127 : q);
        p.c[j] = (signed char)q;
      }
      orow[t + s * 256] = p.i;
    }
    if (t == 0) stp[row] = m * (1.0f / 127.0f);
  } else if (bid < 8512) {
    int i = (bid - 8256) * 256 + t;      // 65536 threads x 4 els
    float4 v = ((const float4*)lB)[i];
    union { __bf16 h[4]; uint64_t u; } p;
    p.h[0] = (__bf16)(2.0f * v.x); p.h[1] = (__bf16)(2.0f * v.y);
    p.h[2] = (__bf16)(2.0f * v.z); p.h[3] = (__bf16)(2.0f * v.w);
    ((uint64_t*)Blt)[i] = p.u;
  } else {
    int i = (bid - 8512) * 256 + t;      // 4.19M threads x 4 els
    int4 v = ((const int4*)qw)[i];
    union { signed char c[4]; int i; } p;
    p.c[0] = (signed char)v.x; p.c[1] = (signed char)v.y;
    p.c[2] = (signed char)v.z; p.c[3] = (signed char)v.w;
    ((int*)Wi8)[i] = p.i;
  }
}

// ---- xa = (Xi8 @ Ai8^T)*tstep*astep -> bf16 [8192][64] ----
__global__ __launch_bounds__(128) void lora_xa_kernel(const signed char* __restrict__ Xi8,
                                                      const float* __restrict__ tstep,
                                                      const signed char* __restrict__ Ai8,
                                                      const float* __restrict__ astep,
                                                      __bf16* __restrict__ xa) {
  int wid = threadIdx.x >> 6, lane = threadIdx.x & 63;
  int rowbase = blockIdx.x * 32 + wid * 16;
  i32x4 acc[4] = {};
  const signed char* xrow = Xi8 + (size_t)(rowbase + (lane & 15)) * DIN + (lane >> 4) * 16;
  const signed char* ab = Ai8 + (size_t)(lane & 15) * DIN + (lane >> 4) * 16;
  for (int k0 = 0; k0 < DIN; k0 += 64) {
    i32x4 af = *(const i32x4*)(xrow + k0);
#pragma unroll
    for (int ni = 0; ni < 4; ++ni) {
      i32x4 bv = *(const i32x4*)(ab + (size_t)ni * 16 * DIN + k0);
      acc[ni] = __builtin_amdgcn_mfma_i32_16x16x64_i8(af, bv, acc[ni], 0, 0, 0);
    }
  }
  f32x4 tm = *(const f32x4*)&tstep[rowbase + (lane >> 4) * 4];
#pragma unroll
  for (int ni = 0; ni < 4; ++ni) {
    const int col = ni * 16 + (lane & 15);
    const float as = astep[col];
#pragma unroll
    for (int j = 0; j < 4; ++j) {
      int row = rowbase + (lane >> 4) * 4 + j;
      xa[(size_t)row * RNK + col] = (__bf16)((float)acc[ni][j] * tm[j] * as);
    }
  }
}

// ==== i8 main GEMM: 256x256, 8 waves x (128x64), 32x32x32 i8, 3-deep LDS ====
// LDS buf (32 KB): A 256x64 i8 @0, B 256x64 i8 @16384. Row r = 64 B = 4 slots
// of 16B; phys slot = logical ^ ((r>>1)&3).
//   Frag read (32x32): lane l -> row base+(l&31), logical slot 2*ks+(l>>5).
//   Conflict-free: lanes 0-7 (rows 0-7) hit banks {0-3,16-19,4-7,20-23,
//   8-11,24-27,12-15,28-31} — all 32 banks per 8-lane group.
// Tile kt (buf cur=kt%3): stage(kt+2)->buf[(cur+2)%3]; 12 ds_read; 16 MFMA;
// vmcnt(4) [tile kt+1 landed, kt+2's 4 stay in flight]; barrier.
__global__ __launch_bounds__(512, 1) void gemm_i8_kernel(const signed char* __restrict__ Xi8,
                                                         const signed char* __restrict__ Wi8,
                                                         const float* __restrict__ scale,
                                                         const float* __restrict__ tstep,
                                                         const __bf16* __restrict__ xa,
                                                         const __bf16* __restrict__ Blt,
                                                         float* __restrict__ out) {
  extern __shared__ char smem[];
  const int tid = threadIdx.x;
  const int lane = tid & 63;
  const int w = tid >> 6;
  const int wr = w >> 2;         // 0..1 -> rows wr*128
  const int wc = w & 3;          // 0..3 -> cols wc*64

  // bijective XCD swizzle (nwg=512, 512%8==0)
  const int swz = (blockIdx.x & 7) * 64 + (blockIdx.x >> 3);
  const int bx = swz & 15;
  const int by = swz >> 4;
  const size_t bm = (size_t)by * 256, bn = (size_t)bx * 256;

  // stage: thread t -> LDS byte t*16 (row t>>2, phys slot t&3); src col from
  // inverse swizzle s_log = (t&3) ^ ((t>>3)&3)
  const int srow = tid >> 2;
  const int scol = ((tid & 3) ^ ((tid >> 3) & 3)) << 4;

  auto SH = [&](const signed char* g, size_t r0, int srct, int ldsoff) {
    gload_lds16(g + (r0 + srow) * (size_t)4096 + srct * 64 + scol,
                smem + ldsoff + tid * 16);
  };
  auto stage = [&](int srct, int buf) {
    int b = buf * BUFB;
    SH(Xi8, bm, srct, b); SH(Xi8, bm + 128, srct, b + 8192);
    SH(Wi8, bn, srct, b + 16384); SH(Wi8, bn + 128, srct, b + 24576);
  };

  // frag-read lane constants (32x32 pattern, 64B rows)
  const int lr64 = (lane & 31) * 64;
  const int lx = (lane >> 1) & 3;
  const int sl0 = ((0 * 2 + (lane >> 5)) ^ lx) << 4;   // ks=0 slot bytes
  const int sl1 = ((1 * 2 + (lane >> 5)) ^ lx) << 4;   // ks=1 slot bytes

  i32x4 a[4][2], b[2][2];
  i32x16 acc[4][2] = {};

  // prologue: tiles 0,1; vmcnt(4) -> tile 0 landed
  stage(0, 0); stage(1, 1);
  asm volatile("s_waitcnt vmcnt(4)" ::: "memory");
  __builtin_amdgcn_s_barrier();

  int cur = 0;
  for (int kt = 0; kt < NT; ++kt) {
    const int bufb = cur * BUFB;
    if (kt < NT - 2) {
      int sb = cur + 2; if (sb >= 3) sb -= 3;
      stage(kt + 2, sb);
    }
    const int ab = bufb + wr * 128 * 64 + lr64;
    const int bb = bufb + 16384 + wc * 64 * 64 + lr64;
#pragma unroll
    for (int mi = 0; mi < 4; ++mi) {
      a[mi][0] = *(const i32x4*)(smem + ab + mi * 2048 + sl0);
      a[mi][1] = *(const i32x4*)(smem + ab + mi * 2048 + sl1);
    }
#pragma unroll
    for (int ni = 0; ni < 2; ++ni) {
      b[ni][0] = *(const i32x4*)(smem + bb + ni * 2048 + sl0);
      b[ni][1] = *(const i32x4*)(smem + bb + ni * 2048 + sl1);
    }
    __builtin_amdgcn_s_setprio(1);
#pragma unroll
    for (int ks = 0; ks < 2; ++ks)
#pragma unroll
      for (int mi = 0; mi < 4; ++mi)
#pragma unroll
        for (int ni = 0; ni < 2; ++ni)
          acc[mi][ni] = __builtin_amdgcn_mfma_i32_32x32x32_i8(a[mi][ks], b[ni][ks], acc[mi][ni], 0, 0, 0);
    __builtin_amdgcn_s_setprio(0);
    __builtin_amdgcn_sched_barrier(0);
    if (kt < NT - 2) { asm volatile("s_waitcnt vmcnt(4)" ::: "memory"); }
    else if (kt == NT - 2) { asm volatile("s_waitcnt vmcnt(0)" ::: "memory"); }
    __builtin_amdgcn_s_barrier();
    ++cur; if (cur >= 3) cur = 0;
  }

  // ---- epilogue: stage xa (32 KB @0) / Blt (32 KB @32768), 128B bf16 rows,
  // phys slot = logical ^ (row&7) ----
  const int erow = tid >> 3;                              // 0..63 rows/instr
  const int ecol = (((tid & 7) ^ ((tid >> 3) & 7)) << 4); // inverse-swz src col
  auto SBF = [&](const __bf16* g, size_t r0, int ldsoff) {
    gload_lds16((const char*)g + (r0 + erow) * 128 + ecol, smem + ldsoff + tid * 16);
  };
  SBF(xa, bm, 0); SBF(xa, bm + 64, 8192);
  SBF(xa, bm + 128, 16384); SBF(xa, bm + 192, 24576);
  SBF(Blt, bn, 32768); SBF(Blt, bn + 64, 40960);
  SBF(Blt, bn + 128, 49152); SBF(Blt, bn + 192, 57344);

  const float sc0 = scale[bn + wc * 64 + (lane & 31)];
  const float sc1 = scale[bn + wc * 64 + 32 + (lane & 31)];

  asm volatile("s_waitcnt vmcnt(0)" ::: "memory");
  __builtin_amdgcn_s_barrier();

  // 32x32x16 bf16 frag reads: row base+(l&31), slot 2*ks+(l>>5), 128B rows
  const int exr = lane & 7;
  const int lr128 = (lane & 31) * 128;
#pragma unroll
  for (int mi = 0; mi < 4; ++mi) {
    const int arow0 = wr * 128 + mi * 32;
    const int abase = arow0 * 128 + lr128;
    f32x4 tm[4];
#pragma unroll
    for (int g = 0; g < 4; ++g)
      tm[g] = *(const f32x4*)&tstep[bm + arow0 + 8 * g + 4 * (lane >> 5)];
#pragma unroll
    for (int ni = 0; ni < 2; ++ni) {
      const int bbase = 32768 + (wc * 64 + ni * 32) * 128 + lr128;
      f32x16 l = {};
#pragma unroll
      for (int ks = 0; ks < 4; ++ks) {
        const int sl = ((2 * ks + (lane >> 5)) ^ exr) << 4;
        bf16x8 ax = *(const bf16x8*)(smem + abase + sl);
        bf16x8 bl = *(const bf16x8*)(smem + bbase + sl);
        l = __builtin_amdgcn_mfma_f32_32x32x16_bf16(ax, bl, l, 0, 0, 0);
      }
      const float scn = ni ? sc1 : sc0;
      const size_t col = bn + wc * 64 + ni * 32 + (lane & 31);
#pragma unroll
      for (int reg = 0; reg < 16; ++reg) {
        const size_t row = bm + arow0 + (reg & 3) + 8 * (reg >> 2) + 4 * (lane >> 5);
        out[row * DOUT + col] = (float)acc[mi][ni][reg] * (scn * tm[reg >> 2][reg & 3]) + l[reg];
      }
    }
  }
}

extern "C" void kernel_launch(void* const* d_in, const int* in_sizes, int n_in,
                              void* d_out, int out_size, void* d_ws, size_t ws_size,
                              hipStream_t stream) {
  const float* x = (const float*)d_in[0];
  const int* qw = (const int*)d_in[1];
  const float* scale = (const float*)d_in[2];
  const float* lA = (const float*)d_in[3];
  const float* lB = (const float*)d_in[4];
  float* out = (float*)d_out;

  char* ws = (char*)d_ws;
  signed char* Xi8 = (signed char*)ws;                              // 33.6 MB
  signed char* Wi8 = (signed char*)(ws + 33554432);                 // 16.8 MB
  __bf16* xa    = (__bf16*)(ws + 50331648);                         // 1.05 MB
  signed char* Ai8 = (signed char*)(ws + 51380224);                 // 0.26 MB
  __bf16* Blt   = (__bf16*)(ws + 51904512);                         // 0.52 MB
  float* tstep  = (float*)(ws + 52428800);                          // 32 KB
  float* astep  = (float*)(ws + 52461568);                          // 256 B

  hipFuncSetAttribute((const void*)gemm_i8_kernel,
                      hipFuncAttributeMaxDynamicSharedMemorySize, 3 * BUFB);

  prep_kernel<<<24896, 256, 0, stream>>>(x, qw, lA, lB, Xi8, tstep, Wi8, Ai8, astep, Blt);
  lora_xa_kernel<<<MTOT / 32, 128, 0, stream>>>(Xi8, tstep, Ai8, astep, xa);
  gemm_i8_kernel<<<(MTOT / 256) * (DOUT / 256), 512, 3 * BUFB, stream>>>(
      Xi8, Wi8, scale, tstep, xa, Blt, out);
}

// Round 10
// 198.679 us; speedup vs baseline: 1.1340x; 1.1340x over previous
//
#include <hip/hip_runtime.h>
#include <hip/hip_bf16.h>
#include <stdint.h>

// LoRA int8-dequant linear, MI355X/gfx950 — int8 main path (R7 GEMM revert).
//   Xi8[8192][4096] = rne(x * 127/absmax_row),  tstep[m] = absmax_row/127
//   Wi8[4096][4096] = qweight codes (exact i8)
//   out = (Xi8 @ Wi8^T)_i32 * (tstep[m]*scale[o]) + xa @ (2B)^T
// Main GEMM: 256x256 tile, BK=64, 8 waves, mfma_i32_16x16x64_i8, 4-deep LDS
// (128 KB), pipelined ds_reads, counted vmcnt(4), no setprio (lockstep).

typedef __bf16 bf16x8 __attribute__((ext_vector_type(8)));
typedef float f32x4 __attribute__((ext_vector_type(4)));
typedef int i32x4 __attribute__((ext_vector_type(4)));

#define DIN   4096
#define DOUT  4096
#define MTOT  8192
#define RNK   64
#define NT    64

__device__ inline void gload_lds16(const void* g, void* l) {
  __builtin_amdgcn_global_load_lds((const __attribute__((address_space(1))) void*)g,
                                   (__attribute__((address_space(3))) void*)l,
                                   16, 0, 0);
}

// ==== merged prep: blocks [0,8192) quant x rows; [8192,8256) quant lora_A
// rows; [8256,8512) Blt = bf16(2*lora_B); [8512,24896) Wi8 = i8(qweight) ====
__global__ __launch_bounds__(256) void prep_kernel(const float* __restrict__ x,
                                                   const int* __restrict__ qw,
                                                   const float* __restrict__ lA,
                                                   const float* __restrict__ lB,
                                                   signed char* __restrict__ Xi8,
                                                   float* __restrict__ tstep,
                                                   signed char* __restrict__ Wi8,
                                                   signed char* __restrict__ Ai8,
                                                   float* __restrict__ astep,
                                                   __bf16* __restrict__ Blt) {
  const int bid = blockIdx.x, t = threadIdx.x;
  const float* src = nullptr;
  signed char* dst = nullptr;
  float* stp = nullptr;
  int row = 0;
  if (bid < 8192) { src = x; dst = Xi8; stp = tstep; row = bid; }
  else if (bid < 8256) { src = lA; dst = Ai8; stp = astep; row = bid - 8192; }
  if (src) {
    const float4* xr = (const float4*)(src + (size_t)row * DIN);
    float4 v[4];
    float m = 0.f;
#pragma unroll
    for (int s = 0; s < 4; ++s) {
      v[s] = xr[t + s * 256];
      m = fmaxf(m, fmaxf(fmaxf(fabsf(v[s].x), fabsf(v[s].y)),
                         fmaxf(fabsf(v[s].z), fabsf(v[s].w))));
    }
#pragma unroll
    for (int off = 32; off > 0; off >>= 1) m = fmaxf(m, __shfl_xor(m, off));
    __shared__ float wm[4];
    if ((t & 63) == 0) wm[t >> 6] = m;
    __syncthreads();
    m = fmaxf(fmaxf(wm[0], wm[1]), fmaxf(wm[2], wm[3]));
    m = fmaxf(m, 1e-30f);
    const float rs = 127.0f / m;
    int* orow = (int*)(dst + (size_t)row * DIN);
#pragma unroll
    for (int s = 0; s < 4; ++s) {
      float e[4] = {v[s].x, v[s].y, v[s].z, v[s].w};
      union { signed char c[4]; int i; } p;
#pragma unroll
      for (int j = 0; j < 4; ++j) {
        int q = __float2int_rn(e[j] * rs);
        q = q > 127 ? 127 : (q < -127 ? -127 : q);
        p.c[j] = (signed char)q;
      }
      orow[t + s * 256] = p.i;
    }
    if (t == 0) stp[row] = m * (1.0f / 127.0f);
  } else if (bid < 8512) {
    int i = (bid - 8256) * 256 + t;
    float4 v = ((const float4*)lB)[i];
    union { __bf16 h[4]; uint64_t u; } p;
    p.h[0] = (__bf16)(2.0f * v.x); p.h[1] = (__bf16)(2.0f * v.y);
    p.h[2] = (__bf16)(2.0f * v.z); p.h[3] = (__bf16)(2.0f * v.w);
    ((uint64_t*)Blt)[i] = p.u;
  } else {
    int i = (bid - 8512) * 256 + t;
    int4 v = ((const int4*)qw)[i];
    union { signed char c[4]; int i; } p;
    p.c[0] = (signed char)v.x; p.c[1] = (signed char)v.y;
    p.c[2] = (signed char)v.z; p.c[3] = (signed char)v.w;
    ((int*)Wi8)[i] = p.i;
  }
}

// ---- xa = (Xi8 @ Ai8^T)*tstep*astep -> bf16 [8192][64] ----
// 512 blocks x 4 waves; wave w owns K in [w*1024,(w+1)*1024); exact i32
// LDS reduce across waves; wave 0 scales + writes.
__global__ __launch_bounds__(256) void lora_xa_kernel(const signed char* __restrict__ Xi8,
                                                      const float* __restrict__ tstep,
                                                      const signed char* __restrict__ Ai8,
                                                      const float* __restrict__ astep,
                                                      __bf16* __restrict__ xa) {
  __shared__ i32x4 red[4][64][4];
  const int w = threadIdx.x >> 6, lane = threadIdx.x & 63;
  const int rowbase = blockIdx.x * 16;
  i32x4 acc[4] = {};
  const int k00 = w * 1024 + (lane >> 4) * 16;
  const signed char* xrow = Xi8 + (size_t)(rowbase + (lane & 15)) * DIN + k00;
  const signed char* ab = Ai8 + (size_t)(lane & 15) * DIN + k00;
#pragma unroll 4
  for (int k = 0; k < 1024; k += 64) {
    i32x4 af = *(const i32x4*)(xrow + k);
#pragma unroll
    for (int ni = 0; ni < 4; ++ni) {
      i32x4 bv = *(const i32x4*)(ab + (size_t)ni * 16 * DIN + k);
      acc[ni] = __builtin_amdgcn_mfma_i32_16x16x64_i8(af, bv, acc[ni], 0, 0, 0);
    }
  }
#pragma unroll
  for (int ni = 0; ni < 4; ++ni) red[w][lane][ni] = acc[ni];
  __syncthreads();
  if (w == 0) {
    f32x4 tm = *(const f32x4*)&tstep[rowbase + (lane >> 4) * 4];
#pragma unroll
    for (int ni = 0; ni < 4; ++ni) {
      i32x4 s = red[0][lane][ni];
#pragma unroll
      for (int u = 1; u < 4; ++u) s += red[u][lane][ni];
      const int col = ni * 16 + (lane & 15);
      const float as = astep[col];
#pragma unroll
      for (int j = 0; j < 4; ++j) {
        int row = rowbase + (lane >> 4) * 4 + j;
        xa[(size_t)row * RNK + col] = (__bf16)((float)s[j] * tm[j] * as);
      }
    }
  }
}

// ==== i8 main GEMM, pipelined (R7 structure, no setprio) ====
// LDS 128 KB: 4 bufs x 32 KB, buf = { A0(8K rows0-127), A1(8K), B0, B1 }.
// Half = 128 rows x 64 i8; row r, 16B-slot s at phys slot s ^ ((r>>1)&3).
// Body(kt): stage(kt+3)->buf[(kt+3)&3]; ds a2(kt); MFMA lo (operands already
// in regs from previous body); ds a/b of buf[(kt+1)&3] -> next-state regs;
// MFMA hi; vmcnt(4); barrier.
__global__ __launch_bounds__(512, 1) void gemm_i8_kernel(const signed char* __restrict__ Xi8,
                                                         const signed char* __restrict__ Wi8,
                                                         const float* __restrict__ scale,
                                                         const float* __restrict__ tstep,
                                                         const __bf16* __restrict__ xa,
                                                         const __bf16* __restrict__ Blt,
                                                         float* __restrict__ out) {
  extern __shared__ char smem[];
  const int tid = threadIdx.x;
  const int lane = tid & 63;
  const int w = tid >> 6;
  const int wr = w >> 2;
  const int wc = w & 3;

  const int swz = (blockIdx.x & 7) * 64 + (blockIdx.x >> 3);
  const int bx = swz & 15;
  const int by = swz >> 4;
  const size_t bm = (size_t)by * 256, bn = (size_t)bx * 256;

  const int rc = ((lane >> 4) ^ ((lane >> 1) & 3)) << 4;
  const int srow = tid >> 2;
  const int scol = ((tid & 3) ^ ((tid >> 3) & 3)) << 4;

  auto SH = [&](const signed char* g, size_t r0, int srct, int ldsoff) {
    gload_lds16(g + (r0 + srow) * (size_t)4096 + srct * 64 + scol,
                smem + ldsoff + tid * 16);
  };
  auto stage = [&](int srct, int buf) {
    int b = buf * 32768;
    SH(Xi8, bm, srct, b); SH(Xi8, bm + 128, srct, b + 8192);
    SH(Wi8, bn, srct, b + 16384); SH(Wi8, bn + 128, srct, b + 24576);
  };

  i32x4 aP[4], bP[4], aQ[4], bQ[4], a2[4];
  i32x4 acc[8][4] = {};

  stage(0, 0); stage(1, 1); stage(2, 2);
  asm volatile("s_waitcnt vmcnt(4)" ::: "memory");
  __builtin_amdgcn_s_barrier();
  {
    const int ab0 = wr * 8192 + (lane & 15) * 64 + rc;
    const int bb0 = 16384 + (wc >> 1) * 8192 + (wc & 1) * 4096 + (lane & 15) * 64 + rc;
#pragma unroll
    for (int mi = 0; mi < 4; ++mi) aP[mi] = *(const i32x4*)(smem + ab0 + mi * 1024);
#pragma unroll
    for (int ni = 0; ni < 4; ++ni) bP[ni] = *(const i32x4*)(smem + bb0 + ni * 1024);
  }

  auto body = [&](int kt, auto& ac, auto& bc, auto& an, auto& bn) {
    const int bufb = (kt & 3) * 32768;
    const int ab = bufb + wr * 8192 + (lane & 15) * 64 + rc;
    const int st = (kt + 3 < NT) ? kt + 3 : NT - 1;
    stage(st, (kt + 3) & 3);
#pragma unroll
    for (int mi = 0; mi < 4; ++mi)
      a2[mi] = *(const i32x4*)(smem + ab + 4096 + mi * 1024);
#pragma unroll
    for (int mi = 0; mi < 4; ++mi)
#pragma unroll
      for (int ni = 0; ni < 4; ++ni)
        acc[mi][ni] = __builtin_amdgcn_mfma_i32_16x16x64_i8(ac[mi], bc[ni], acc[mi][ni], 0, 0, 0);
    const int nbufb = ((kt + 1) & 3) * 32768;
    const int nab = nbufb + wr * 8192 + (lane & 15) * 64 + rc;
    const int nbb = nbufb + 16384 + (wc >> 1) * 8192 + (wc & 1) * 4096 + (lane & 15) * 64 + rc;
#pragma unroll
    for (int mi = 0; mi < 4; ++mi) an[mi] = *(const i32x4*)(smem + nab + mi * 1024);
#pragma unroll
    for (int ni = 0; ni < 4; ++ni) bn[ni] = *(const i32x4*)(smem + nbb + ni * 1024);
#pragma unroll
    for (int mi = 0; mi < 4; ++mi)
#pragma unroll
      for (int ni = 0; ni < 4; ++ni)
        acc[4 + mi][ni] = __builtin_amdgcn_mfma_i32_16x16x64_i8(a2[mi], bc[ni], acc[4 + mi][ni], 0, 0, 0);
    __builtin_amdgcn_sched_barrier(0);
    asm volatile("s_waitcnt vmcnt(4)" ::: "memory");
    __builtin_amdgcn_s_barrier();
  };

  for (int kt = 0; kt < NT; kt += 2) {
    body(kt, aP, bP, aQ, bQ);
    body(kt + 1, aQ, bQ, aP, bP);
  }

  // ---- epilogue: stage xa/Blt (bf16, rows of 128B, phys slot = log ^ (r&7)) ----
  const int sl_row = lane >> 3;
  const int sl_col = ((lane & 7) ^ (lane >> 3)) << 4;
  auto SBF = [&](const __bf16* g, size_t r0, int ldsoff) {
    char* d0 = smem + ldsoff + w * 2048 + lane * 16;
#pragma unroll
    for (int s = 0; s < 2; ++s) {
      const int rl = (w * 2 + s) * 8 + sl_row;
      gload_lds16((const char*)g + (r0 + rl) * 128 + sl_col, d0 + s * 1024);
    }
  };
  SBF(xa, bm, 0); SBF(xa, bm + 128, 16384);
  SBF(Blt, bn, 32768); SBF(Blt, bn + 128, 49152);

  float sc[4];
#pragma unroll
  for (int ni = 0; ni < 4; ++ni)
    sc[ni] = scale[bn + wc * 64 + ni * 16 + (lane & 15)];
  f32x4 tm[8];
#pragma unroll
  for (int mi = 0; mi < 8; ++mi)
    tm[mi] = *(const f32x4*)&tstep[bm + wr * 128 + mi * 16 + (lane >> 4) * 4];

  asm volatile("s_waitcnt vmcnt(0)" ::: "memory");
  __builtin_amdgcn_s_barrier();

  const int cx0 = ((lane >> 4) << 4) ^ ((lane & 7) << 4);
  const int cx1 = (64 | ((lane >> 4) << 4)) ^ ((lane & 7) << 4);
  const int abE = wr * 16384 + (lane & 15) * 128;
  const int bbE = 32768 + (wc >> 1) * 16384 + ((wc & 1) * 64 + (lane & 15)) * 128;

  bf16x8 bl0[4], bl1[4];
#pragma unroll
  for (int ni = 0; ni < 4; ++ni) {
    bl0[ni] = *(const bf16x8*)(smem + bbE + ni * 2048 + cx0);
    bl1[ni] = *(const bf16x8*)(smem + bbE + ni * 2048 + cx1);
  }
#pragma unroll
  for (int mi = 0; mi < 8; ++mi) {
    bf16x8 ax0 = *(const bf16x8*)(smem + abE + mi * 2048 + cx0);
    bf16x8 ax1 = *(const bf16x8*)(smem + abE + mi * 2048 + cx1);
    const size_t row = bm + wr * 128 + mi * 16 + (lane >> 4) * 4;
#pragma unroll
    for (int ni = 0; ni < 4; ++ni) {
      f32x4 l = {0.f, 0.f, 0.f, 0.f};
      l = __builtin_amdgcn_mfma_f32_16x16x32_bf16(ax0, bl0[ni], l, 0, 0, 0);
      l = __builtin_amdgcn_mfma_f32_16x16x32_bf16(ax1, bl1[ni], l, 0, 0, 0);
      const size_t col = bn + wc * 64 + ni * 16 + (lane & 15);
#pragma unroll
      for (int j = 0; j < 4; ++j)
        out[(row + j) * DOUT + col] = (float)acc[mi][ni][j] * (sc[ni] * tm[mi][j]) + l[j];
    }
  }
}

extern "C" void kernel_launch(void* const* d_in, const int* in_sizes, int n_in,
                              void* d_out, int out_size, void* d_ws, size_t ws_size,
                              hipStream_t stream) {
  const float* x = (const float*)d_in[0];
  const int* qw = (const int*)d_in[1];
  const float* scale = (const float*)d_in[2];
  const float* lA = (const float*)d_in[3];
  const float* lB = (const float*)d_in[4];
  float* out = (float*)d_out;

  char* ws = (char*)d_ws;
  signed char* Xi8 = (signed char*)ws;                              // 33.6 MB
  signed char* Wi8 = (signed char*)(ws + 33554432);                 // 16.8 MB
  __bf16* xa    = (__bf16*)(ws + 50331648);                         // 1.05 MB
  signed char* Ai8 = (signed char*)(ws + 51380224);                 // 0.26 MB
  __bf16* Blt   = (__bf16*)(ws + 51904512);                         // 0.52 MB
  float* tstep  = (float*)(ws + 52428800);                          // 32 KB
  float* astep  = (float*)(ws + 52461568);                          // 256 B

  hipFuncSetAttribute((const void*)gemm_i8_kernel,
                      hipFuncAttributeMaxDynamicSharedMemorySize, 131072);

  prep_kernel<<<24896, 256, 0, stream>>>(x, qw, lA, lB, Xi8, tstep, Wi8, Ai8, astep, Blt);
  lora_xa_kernel<<<MTOT / 16, 256, 0, stream>>>(Xi8, tstep, Ai8, astep, xa);
  gemm_i8_kernel<<<(MTOT / 256) * (DOUT / 256), 512, 131072, stream>>>(
      Xi8, Wi8, scale, tstep, xa, Blt, out);
}